// Round 9
// baseline (100.810 us; speedup 1.0000x reference)
//
#include <hip/hip_runtime.h>
#include <math.h>

#define FD 76
#define FFD 5776
#define BD 16
#define CD 256
#define KD 50
#define AD 3

typedef float f32x2 __attribute__((ext_vector_type(2)));
typedef float f32x4 __attribute__((ext_vector_type(4)));

constexpr int NCELL = BD * FFD;          // 92416
constexpr int QBLK = 361;                // cells per block (5776 = 16*361)
constexpr int NBLK = 256;                // 16 b x 16 q

// ws layout (float offsets)
constexpr int ACC_O   = 0;               // [8]: [3]=lcls, [4]=l2cls (cls-kernel atomics)
constexpr int CNT_O   = 8;               // [1] int match counter
constexpr int LIST_O  = 16;              // [1024][2] ints (cA, cls)
constexpr int TREC_O  = 2064;            // [800][16] per-(b,k) records (16B aligned)
constexpr int WP_O    = TREC_O + 800*16; // [256][16] reordered W' (16B aligned)
constexpr int BLK_O   = WP_O + 4096;     // [NBLK*4] per-block loss partials
constexpr int VBUF_O  = 65536;           // [92416][16] conv outputs (16B aligned)
constexpr int PROBE_O = VBUF_O + NCELL*16; // [2048] probe sums

__device__ __forceinline__ float sigm(float x){ return 1.f/(1.f + expf(-x)); }
__device__ __forceinline__ float clg(float x){ return logf(fmaxf(x, 1e-12f)); }
__device__ __forceinline__ float bce(float o, float t){ return -(t*clg(o) + (1.f-t)*clg(1.f-o)); }

// ---------------- probe: m13-clone dense stream over xin (diagnostic) -----------------
__global__ __launch_bounds__(256) void probe_kernel(const f32x4* __restrict__ x,
                                                    float* __restrict__ ws){
  __shared__ float sm[256];
  const int tid = threadIdx.x;
  f32x4 a = {0,0,0,0};
  const size_t n = (size_t)BD*CD*FFD/4;           // 5,914,624 float4s
  for (size_t i = (size_t)blockIdx.x*256 + tid; i < n; i += (size_t)2048*256)
    a += x[i];
  sm[tid] = a.x + a.y + a.z + a.w;
  __syncthreads();
  for (int s = 128; s > 0; s >>= 1){ if (tid < s) sm[tid] += sm[tid+s]; __syncthreads(); }
  if (tid == 0) ws[PROBE_O + blockIdx.x] = sm[0];
}

// record layout [16]: 0:tx0 1:tx1 2:ty0 3:ty1 4:c7(0.7*ta|1e30) 5:code 6:txf 7:tyf
//                     8:twl 9:thl 10:scale 11:cls 12..15 pad
__global__ __launch_bounds__(256) void label_kernel(const float* __restrict__ labels,
                                                    const float* __restrict__ cw,
                                                    float* __restrict__ ws){
  if (blockIdx.x == 4){                  // build W'[c][16]: W'[c*16+j] = cw[o(j)*256+c]
    const int c = threadIdx.x;
    #pragma unroll
    for (int j = 0; j < 15; ++j){
      const int o = (j/5)*85 + (j%5);
      ws[WP_O + c*16 + j] = cw[o*CD + c];
    }
    ws[WP_O + c*16 + 15] = 0.f;
    return;
  }
  const int it = blockIdx.x*256 + threadIdx.x;
  if (blockIdx.x == 0 && threadIdx.x < 9){
    if (threadIdx.x < 8) ws[ACC_O + threadIdx.x] = 0.f;
    else ((int*)ws)[CNT_O] = 0;
  }
  if (it >= BD*KD) return;
  const float AWH[9][2] = {{1.25f,1.625f},{2.f,3.75f},{4.125f,2.875f},
                           {3.75f,7.625f},{7.75f,5.625f},{7.375f,14.875f},
                           {14.5f,11.25f},{19.5f,24.75f},{46.625f,40.75f}};
  const float* l = labels + it*5;
  const float cls = l[0], x = l[1], y = l[2], w = l[3], h = l[4];
  const bool valid = (cls + x + y + w + h) > 0.f;
  const float tx = x*FD, ty = y*FD, tw = w*FD, th = h*FD;
  const float ta = tw*th;
  float bestv = -1.f; int best = 0;
  #pragma unroll
  for (int n = 0; n < 9; ++n){
    const float mw = fminf(tw, AWH[n][0]), mh = fminf(th, AWH[n][1]);
    const float inter = (mw > 0.f && mh > 0.f) ? mw*mh : 0.f;
    const float iou = inter / (ta + AWH[n][0]*AWH[n][1] - inter);
    if (iou > bestv){ bestv = iou; best = n; }
  }
  const int bn = best % 3;
  const bool match = valid && (best < 3);
  const int ii = (int)tx, jj = (int)ty;
  const bool inb = (ii >= 0 && ii < FD && jj >= 0 && jj < FD);
  const float code = (match && inb) ? (float)(bn*FFD + jj*FD + ii) : -1.f;
  const float aw0 = (bn==0)?1.25f:((bn==1)?2.f:4.125f);
  const float aw1 = (bn==0)?1.625f:((bn==1)?3.75f:2.875f);
  float* r = ws + TREC_O + it*16;
  f32x4 r0 = {tx - tw*0.5f, tx + tw*0.5f, ty - th*0.5f, ty + th*0.5f};
  f32x4 r1 = {valid ? 0.7f*ta : 1e30f, code, tx - floorf(tx), ty - floorf(ty)};
  f32x4 r2 = {logf(tw/aw0 + 1e-16f), logf(th/aw1 + 1e-16f),
              sqrtf(2.f - ta/(float)(FD*FD)), cls};
  f32x4 r3 = {0.f, 0.f, 0.f, 0.f};
  *(f32x4*)(r+0) = r0; *(f32x4*)(r+4) = r1; *(f32x4*)(r+8) = r2; *(f32x4*)(r+12) = r3;
}

// ---------------- conv only: r8 hot loop, epilogue removed, writes vbuf ---------------
__global__ __launch_bounds__(384) void conv_kernel(const float* __restrict__ xin,
    const float* __restrict__ wp, float* __restrict__ vbuf){
  const int tid = threadIdx.x;
  const int bid = blockIdx.x;
  const int b = ((bid & 7) << 1) | ((bid >> 3) & 1);
  const int q = bid >> 4;
  if (tid >= QBLK) return;
  const int hw = q*QBLK + tid;
  const float* xrow = xin + (size_t)b*CD*FFD + hw;

  float acc[15];
  #pragma unroll
  for (int j = 0; j < 15; ++j) acc[j] = 0.f;

  for (int c0 = 0; c0 < CD; c0 += 16){
    float xr[16];
    #pragma unroll
    for (int i = 0; i < 16; ++i)
      xr[i] = xrow[(size_t)(c0 + i)*FFD];
    #pragma unroll
    for (int i = 0; i < 16; ++i){
      const float* wr = wp + (c0 + i)*16;     // uniform -> scalar path
      #pragma unroll
      for (int j = 0; j < 15; ++j) acc[j] += wr[j]*xr[i];
    }
  }
  float* vout = vbuf + (size_t)(b*FFD + hw)*16;
  f32x4 o0 = {acc[0], acc[1], acc[2], acc[3]};
  f32x4 o1 = {acc[4], acc[5], acc[6], acc[7]};
  f32x4 o2 = {acc[8], acc[9], acc[10], acc[11]};
  f32x4 o3 = {acc[12], acc[13], acc[14], 0.f};
  *(f32x4*)(vout+0) = o0; *(f32x4*)(vout+4) = o1;
  *(f32x4*)(vout+8) = o2; *(f32x4*)(vout+12) = o3;
}

// ---------------- epilogue only: reads vbuf, match/IoU/losses -------------------------
__global__ __launch_bounds__(384) void epi_kernel(const float* __restrict__ vbuf,
    const float* __restrict__ cb, float* __restrict__ ws,
    const float* __restrict__ trecg){
  __shared__ __align__(16) float trec[800];
  __shared__ float redc[24];
  const int tid  = threadIdx.x;
  const int wv   = tid >> 6;
  const int lane = tid & 63;
  const int bid  = blockIdx.x;
  const int b = ((bid & 7) << 1) | ((bid >> 3) & 1);
  const int q = bid >> 4;

  if (tid < 200) ((f32x4*)trec)[tid] = ((const f32x4*)(trecg + b*800))[tid];
  __syncthreads();

  float lxy = 0.f, lwh = 0.f, lobj = 0.f, l2p = 0.f;
  if (tid < QBLK){
    const int hw = q*QBLK + tid;
    const int hh = hw / FD, wc = hw - hh*FD;
    const float* vv = vbuf + (size_t)(b*FFD + hw)*16;
    const f32x4 u0 = *(const f32x4*)(vv+0),  u1 = *(const f32x4*)(vv+4);
    const f32x4 u2 = *(const f32x4*)(vv+8),  u3 = *(const f32x4*)(vv+12);
    const float uf[15] = {u0.x,u0.y,u0.z,u0.w, u1.x,u1.y,u1.z,u1.w,
                          u2.x,u2.y,u2.z,u2.w, u3.x,u3.y,u3.z};
    float v[3][5];
    #pragma unroll
    for (int a = 0; a < 3; ++a)
      #pragma unroll
      for (int jj = 0; jj < 5; ++jj)
        v[a][jj] = uf[a*5 + jj] + cb[a*85 + jj];

    const float MW0[3] = {1.25f, 2.f, 4.125f};
    const float MW1[3] = {1.625f, 3.75f, 2.875f};
    float sx[3], sy[3], so[3], pxa[3], pxb[3], pya[3], pyb[3], s7[3], code[3], mx[3];
    int ks[3];
    #pragma unroll
    for (int a = 0; a < 3; ++a){
      sx[a] = sigm(v[a][0]); sy[a] = sigm(v[a][1]); so[a] = sigm(v[a][4]);
      const float pw = expf(v[a][2])*MW0[a], ph = expf(v[a][3])*MW1[a];
      pxa[a] = sx[a] + wc - pw*0.5f; pxb[a] = sx[a] + wc + pw*0.5f;
      pya[a] = sy[a] + hh - ph*0.5f; pyb[a] = sy[a] + hh + ph*0.5f;
      s7[a]  = 0.7f*pw*ph;
      code[a] = (float)(a*FFD + hw);
      mx[a] = -1e30f; ks[a] = -1;
    }
    for (int k = 0; k < KD; ++k){
      const f32x4 rA = *(const f32x4*)&trec[k*16];      // tx0 tx1 ty0 ty1
      const f32x2 rB = *(const f32x2*)&trec[k*16 + 4];  // c7, code
      #pragma unroll
      for (int a = 0; a < 3; ++a){
        const float dx = fminf(pxb[a], rA.y) - fmaxf(pxa[a], rA.x);
        const float dy = fminf(pyb[a], rA.w) - fmaxf(pya[a], rA.z);
        const float inter = fmaxf(dx, 0.f)*fmaxf(dy, 0.f);
        mx[a] = fmaxf(mx[a], 1.7f*inter - rB.x);
        ks[a] = (rB.y == code[a]) ? k : ks[a];
      }
    }
    #pragma unroll
    for (int a = 0; a < 3; ++a){
      if (ks[a] >= 0){
        const float txf = trec[ks[a]*16+6], tyf = trec[ks[a]*16+7];
        const float twl = trec[ks[a]*16+8], thl = trec[ks[a]*16+9];
        const float sc  = trec[ks[a]*16+10], sc2 = sc*sc;
        lxy += sc2*(bce(sx[a], txf) + bce(sy[a], tyf));
        l2p += (sx[a]-txf)*(sx[a]-txf) + (sy[a]-tyf)*(sy[a]-tyf);
        const float d0 = v[a][2]-twl, d1 = v[a][3]-thl;
        lwh += 0.5f*sc2*(d0*d0 + d1*d1);
        l2p += sc2*(d0*d0 + d1*d1);
        lobj += -clg(so[a]); l2p += (so[a]-1.f)*(so[a]-1.f);
        const int pos = atomicAdd((int*)ws + CNT_O, 1);
        if (pos < 1024){ ((int*)ws)[LIST_O + pos*2] = (b*AD + a)*FFD + hw;
                         ((int*)ws)[LIST_O + pos*2 + 1] = (int)trec[ks[a]*16+11]; }
      } else if (!(mx[a] > s7[a])){ lobj += -clg(1.f - so[a]); l2p += so[a]*so[a]; }
    }
  }

  #pragma unroll
  for (int o = 32; o > 0; o >>= 1){
    lxy  += __shfl_down(lxy,  o, 64);
    lwh  += __shfl_down(lwh,  o, 64);
    lobj += __shfl_down(lobj, o, 64);
    l2p  += __shfl_down(l2p,  o, 64);
  }
  __syncthreads();
  if (lane == 0){
    redc[wv*4+0] = lxy; redc[wv*4+1] = lwh; redc[wv*4+2] = lobj; redc[wv*4+3] = l2p;
  }
  __syncthreads();
  if (tid < 4){
    float s = 0.f;
    #pragma unroll
    for (int w = 0; w < 6; ++w) s += redc[w*4 + tid];
    ws[BLK_O + bid*4 + tid] = s;
  }
}

// ---------------- cls kernel: 80 channels at matched cells only -----------------------
__global__ __launch_bounds__(128) void cls_kernel(const float* __restrict__ xin,
    const float* __restrict__ cw, const float* __restrict__ cb, float* __restrict__ ws){
  const int cnt = ((const int*)ws)[CNT_O];
  if ((int)blockIdx.x >= cnt) return;
  const int cA  = ((const int*)ws)[LIST_O + blockIdx.x*2];
  const int cls = ((const int*)ws)[LIST_O + blockIdx.x*2 + 1];
  const int b   = cA / (AD*FFD);
  const int rem = cA - b*AD*FFD;
  const int a   = rem / FFD;
  const int hw  = rem - a*FFD;
  __shared__ float xs[256];
  __shared__ float sm[128];
  const int tid = threadIdx.x;
  const float* xb = xin + ((size_t)b*CD)*FFD + hw;
  xs[tid]       = xb[(size_t)tid*FFD];
  xs[tid + 128] = xb[(size_t)(tid + 128)*FFD];
  __syncthreads();
  float lcls = 0.f, l2p = 0.f;
  if (tid < 80){
    const int o = a*85 + 5 + tid;
    const float* wr = cw + o*CD;
    float s = 0.f;
    #pragma unroll 8
    for (int c = 0; c < CD; ++c) s += xs[c]*wr[c];
    const float e = sigm(s + cb[o]);
    const float t = (tid == cls) ? 1.f : 0.f;
    lcls = bce(e, t);
    l2p  = (e - t)*(e - t);
  }
  sm[tid] = lcls; __syncthreads();
  for (int s2 = 64; s2 > 0; s2 >>= 1){ if (tid < s2) sm[tid] += sm[tid+s2]; __syncthreads(); }
  if (tid == 0) atomicAdd(ws + ACC_O + 3, sm[0]);
  __syncthreads();
  sm[tid] = l2p; __syncthreads();
  for (int s2 = 64; s2 > 0; s2 >>= 1){ if (tid < s2) sm[tid] += sm[tid+s2]; __syncthreads(); }
  if (tid == 0) atomicAdd(ws + ACC_O + 4, sm[0]);
}

// ---------------- finalize ------------------------------------------------------------
__global__ __launch_bounds__(256) void fin_kernel(const float* __restrict__ ws,
                                                  float* __restrict__ out){
  __shared__ float sm[256];
  const int tid = threadIdx.x;
  float p[4];
  #pragma unroll
  for (int r = 0; r < 4; ++r) p[r] = ws[BLK_O + tid*4 + r];
  float tot[4];
  #pragma unroll
  for (int r = 0; r < 4; ++r){
    __syncthreads();
    sm[tid] = p[r];
    __syncthreads();
    for (int s = 128; s > 0; s >>= 1){
      if (tid < s) sm[tid] += sm[tid + s];
      __syncthreads();
    }
    tot[r] = sm[0];
  }
  if (tid == 0){
    const float lxy = tot[0], lwh = tot[1], lobj = tot[2];
    const float lcls = ws[ACC_O+3];
    const float l2   = tot[3] + ws[ACC_O+4];
    out[0] = lxy + lwh + lobj + lcls;
    out[1] = lxy; out[2] = lwh; out[3] = lobj; out[4] = lcls; out[5] = l2;
  }
}

extern "C" void kernel_launch(void* const* d_in, const int* in_sizes, int n_in,
                              void* d_out, int out_size, void* d_ws, size_t ws_size,
                              hipStream_t stream){
  const float* xin    = (const float*)d_in[0];
  const float* labels = (const float*)d_in[1];
  const float* cw     = (const float*)d_in[2];
  const float* cb     = (const float*)d_in[3];
  float* out = (float*)d_out;
  float* ws  = (float*)d_ws;

  probe_kernel<<<2048, 256, 0, stream>>>((const f32x4*)xin, ws);
  label_kernel<<<5, 256, 0, stream>>>(labels, cw, ws);
  conv_kernel<<<NBLK, 384, 0, stream>>>(xin, ws + WP_O, ws + VBUF_O);
  epi_kernel<<<NBLK, 384, 0, stream>>>(ws + VBUF_O, cb, ws, ws + TREC_O);
  cls_kernel<<<800, 128, 0, stream>>>(xin, cw, cb, ws);
  fin_kernel<<<1, 256, 0, stream>>>(ws, out);
}

// Round 10
// 94.138 us; speedup vs baseline: 1.0709x; 1.0709x over previous
//
#include <hip/hip_runtime.h>
#include <math.h>

#define FD 76
#define FFD 5776
#define BD 16
#define CD 256
#define KD 50
#define AD 3

typedef float f32x2 __attribute__((ext_vector_type(2)));
typedef float f32x4 __attribute__((ext_vector_type(4)));
typedef unsigned short u16x4 __attribute__((ext_vector_type(4)));

constexpr int NCELL = BD * FFD;          // 92416
constexpr int QBLK = 361;                // cells per block (5776 = 16*361)
constexpr int NBLK = 256;                // 16 b x 16 q

// ws layout (float offsets)
constexpr int ACC_O   = 0;               // [8]: [3]=lcls, [4]=l2cls (cls-kernel atomics)
constexpr int CNT_O   = 8;               // [1] int match counter
constexpr int LIST_O  = 16;              // [1024][2] ints (cA, cls)
constexpr int TREC_O  = 2064;            // [800][16] per-(b,k) records (16B aligned)
constexpr int WP_O    = TREC_O + 800*16; // [256][16] reordered W' (16B aligned)
constexpr int BLK_O   = WP_O + 4096;     // [NBLK*4] per-block loss partials
constexpr int XBF_O   = 65536;           // bf16 xin copy: 23.66M ushorts = 47.3 MB

__device__ __forceinline__ float sigm(float x){ return 1.f/(1.f + expf(-x)); }
__device__ __forceinline__ float clg(float x){ return logf(fmaxf(x, 1e-12f)); }
__device__ __forceinline__ float bce(float o, float t){ return -(t*clg(o) + (1.f-t)*clg(1.f-o)); }
__device__ __forceinline__ float bf2f(unsigned short us){
  union { unsigned u; float f; } c; c.u = ((unsigned)us) << 16; return c.f;
}

// ---------------- convert: sequential fp32 -> bf16 (RNE), diagnostic + compaction -----
__global__ __launch_bounds__(256) void convert_kernel(const f32x4* __restrict__ x,
                                                      unsigned short* __restrict__ xb){
  const size_t n = (size_t)BD*CD*FFD/4;           // 5,914,624 float4s
  for (size_t i = (size_t)blockIdx.x*256 + threadIdx.x; i < n; i += (size_t)2048*256){
    const f32x4 v = x[i];
    u16x4 o;
    #pragma unroll
    for (int j = 0; j < 4; ++j){
      union { float f; unsigned u; } c; c.f = v[j];
      unsigned u = c.u + (0x7FFFu + ((c.u >> 16) & 1u));   // round-nearest-even
      o[j] = (unsigned short)(u >> 16);
    }
    ((u16x4*)xb)[i] = o;
  }
}

// record layout [16]: 0:tx0 1:tx1 2:ty0 3:ty1 4:c7(0.7*ta|1e30) 5:code 6:txf 7:tyf
//                     8:twl 9:thl 10:scale 11:cls 12..15 pad
__global__ __launch_bounds__(256) void label_kernel(const float* __restrict__ labels,
                                                    const float* __restrict__ cw,
                                                    float* __restrict__ ws){
  if (blockIdx.x == 4){                  // build W'[c][16]: W'[c*16+j] = cw[o(j)*256+c]
    const int c = threadIdx.x;
    #pragma unroll
    for (int j = 0; j < 15; ++j){
      const int o = (j/5)*85 + (j%5);
      ws[WP_O + c*16 + j] = cw[o*CD + c];
    }
    ws[WP_O + c*16 + 15] = 0.f;
    return;
  }
  const int it = blockIdx.x*256 + threadIdx.x;
  if (blockIdx.x == 0 && threadIdx.x < 9){
    if (threadIdx.x < 8) ws[ACC_O + threadIdx.x] = 0.f;
    else ((int*)ws)[CNT_O] = 0;
  }
  if (it >= BD*KD) return;
  const float AWH[9][2] = {{1.25f,1.625f},{2.f,3.75f},{4.125f,2.875f},
                           {3.75f,7.625f},{7.75f,5.625f},{7.375f,14.875f},
                           {14.5f,11.25f},{19.5f,24.75f},{46.625f,40.75f}};
  const float* l = labels + it*5;
  const float cls = l[0], x = l[1], y = l[2], w = l[3], h = l[4];
  const bool valid = (cls + x + y + w + h) > 0.f;
  const float tx = x*FD, ty = y*FD, tw = w*FD, th = h*FD;
  const float ta = tw*th;
  float bestv = -1.f; int best = 0;
  #pragma unroll
  for (int n = 0; n < 9; ++n){
    const float mw = fminf(tw, AWH[n][0]), mh = fminf(th, AWH[n][1]);
    const float inter = (mw > 0.f && mh > 0.f) ? mw*mh : 0.f;
    const float iou = inter / (ta + AWH[n][0]*AWH[n][1] - inter);
    if (iou > bestv){ bestv = iou; best = n; }
  }
  const int bn = best % 3;
  const bool match = valid && (best < 3);
  const int ii = (int)tx, jj = (int)ty;
  const bool inb = (ii >= 0 && ii < FD && jj >= 0 && jj < FD);
  const float code = (match && inb) ? (float)(bn*FFD + jj*FD + ii) : -1.f;
  const float aw0 = (bn==0)?1.25f:((bn==1)?2.f:4.125f);
  const float aw1 = (bn==0)?1.625f:((bn==1)?3.75f:2.875f);
  float* r = ws + TREC_O + it*16;
  f32x4 r0 = {tx - tw*0.5f, tx + tw*0.5f, ty - th*0.5f, ty + th*0.5f};
  f32x4 r1 = {valid ? 0.7f*ta : 1e30f, code, tx - floorf(tx), ty - floorf(ty)};
  f32x4 r2 = {logf(tw/aw0 + 1e-16f), logf(th/aw1 + 1e-16f),
              sqrtf(2.f - ta/(float)(FD*FD)), cls};
  f32x4 r3 = {0.f, 0.f, 0.f, 0.f};
  *(f32x4*)(r+0) = r0; *(f32x4*)(r+4) = r1; *(f32x4*)(r+8) = r2; *(f32x4*)(r+12) = r3;
}

// ---------------- fused conv (bf16 input) + epilogue: r8 structure, half the lines ----
__global__ __launch_bounds__(384) void fused_kernel(const unsigned short* __restrict__ xbf,
    const float* __restrict__ wp, const float* __restrict__ cb,
    float* __restrict__ ws, const float* __restrict__ trecg){
  __shared__ __align__(16) float trec[800];
  __shared__ float redc[24];
  const int tid  = threadIdx.x;
  const int wv   = tid >> 6;
  const int lane = tid & 63;
  const int bid  = blockIdx.x;
  const int b = ((bid & 7) << 1) | ((bid >> 3) & 1);
  const int q = bid >> 4;
  const int hw0 = q * QBLK;

  if (tid < 200) ((f32x4*)trec)[tid] = ((const f32x4*)(trecg + b*800))[tid];
  __syncthreads();

  const bool act = (tid < QBLK);
  const int  hw  = hw0 + (act ? tid : 0);
  const unsigned short* xrow = xbf + (size_t)b*CD*FFD + hw;

  float acc[15];
  #pragma unroll
  for (int j = 0; j < 15; ++j) acc[j] = 0.f;

  if (act){
    for (int c0 = 0; c0 < CD; c0 += 16){
      unsigned short us[16];
      #pragma unroll
      for (int i = 0; i < 16; ++i)            // 16 independent row loads (bf16)
        us[i] = xrow[(size_t)(c0 + i)*FFD];
      #pragma unroll
      for (int i = 0; i < 16; ++i){
        const float xv = bf2f(us[i]);
        const float* wr = wp + (c0 + i)*16;   // uniform -> scalar path
        #pragma unroll
        for (int j = 0; j < 15; ++j) acc[j] += wr[j]*xv;
      }
    }
  }

  // ---- per-thread epilogue: 3 anchors share one 50-record k-loop ----
  float lxy = 0.f, lwh = 0.f, lobj = 0.f, l2p = 0.f;
  if (act){
    const int hh = hw / FD, wc = hw - hh*FD;
    float v[3][5];
    #pragma unroll
    for (int a = 0; a < 3; ++a)
      #pragma unroll
      for (int jj = 0; jj < 5; ++jj)
        v[a][jj] = acc[a*5 + jj] + cb[a*85 + jj];

    const float MW0[3] = {1.25f, 2.f, 4.125f};
    const float MW1[3] = {1.625f, 3.75f, 2.875f};
    float sx[3], sy[3], so[3], pxa[3], pxb[3], pya[3], pyb[3], s7[3], code[3], mx[3];
    int ks[3];
    #pragma unroll
    for (int a = 0; a < 3; ++a){
      sx[a] = sigm(v[a][0]); sy[a] = sigm(v[a][1]); so[a] = sigm(v[a][4]);
      const float pw = expf(v[a][2])*MW0[a], ph = expf(v[a][3])*MW1[a];
      pxa[a] = sx[a] + wc - pw*0.5f; pxb[a] = sx[a] + wc + pw*0.5f;
      pya[a] = sy[a] + hh - ph*0.5f; pyb[a] = sy[a] + hh + ph*0.5f;
      s7[a]  = 0.7f*pw*ph;
      code[a] = (float)(a*FFD + hw);
      mx[a] = -1e30f; ks[a] = -1;
    }
    for (int k = 0; k < KD; ++k){
      const f32x4 rA = *(const f32x4*)&trec[k*16];      // tx0 tx1 ty0 ty1
      const f32x2 rB = *(const f32x2*)&trec[k*16 + 4];  // c7, code
      #pragma unroll
      for (int a = 0; a < 3; ++a){
        const float dx = fminf(pxb[a], rA.y) - fmaxf(pxa[a], rA.x);
        const float dy = fminf(pyb[a], rA.w) - fmaxf(pya[a], rA.z);
        const float inter = fmaxf(dx, 0.f)*fmaxf(dy, 0.f);
        mx[a] = fmaxf(mx[a], 1.7f*inter - rB.x);
        ks[a] = (rB.y == code[a]) ? k : ks[a];
      }
    }
    #pragma unroll
    for (int a = 0; a < 3; ++a){
      if (ks[a] >= 0){
        const float txf = trec[ks[a]*16+6], tyf = trec[ks[a]*16+7];
        const float twl = trec[ks[a]*16+8], thl = trec[ks[a]*16+9];
        const float sc  = trec[ks[a]*16+10], sc2 = sc*sc;
        lxy += sc2*(bce(sx[a], txf) + bce(sy[a], tyf));
        l2p += (sx[a]-txf)*(sx[a]-txf) + (sy[a]-tyf)*(sy[a]-tyf);
        const float d0 = v[a][2]-twl, d1 = v[a][3]-thl;
        lwh += 0.5f*sc2*(d0*d0 + d1*d1);
        l2p += sc2*(d0*d0 + d1*d1);
        lobj += -clg(so[a]); l2p += (so[a]-1.f)*(so[a]-1.f);
        const int pos = atomicAdd((int*)ws + CNT_O, 1);
        if (pos < 1024){ ((int*)ws)[LIST_O + pos*2] = (b*AD + a)*FFD + hw;
                         ((int*)ws)[LIST_O + pos*2 + 1] = (int)trec[ks[a]*16+11]; }
      } else if (!(mx[a] > s7[a])){ lobj += -clg(1.f - so[a]); l2p += so[a]*so[a]; }
    }
  }

  #pragma unroll
  for (int o = 32; o > 0; o >>= 1){
    lxy  += __shfl_down(lxy,  o, 64);
    lwh  += __shfl_down(lwh,  o, 64);
    lobj += __shfl_down(lobj, o, 64);
    l2p  += __shfl_down(l2p,  o, 64);
  }
  __syncthreads();
  if (lane == 0){
    redc[wv*4+0] = lxy; redc[wv*4+1] = lwh; redc[wv*4+2] = lobj; redc[wv*4+3] = l2p;
  }
  __syncthreads();
  if (tid < 4){
    float s = 0.f;
    #pragma unroll
    for (int w = 0; w < 6; ++w) s += redc[w*4 + tid];
    ws[BLK_O + bid*4 + tid] = s;
  }
}

// ---------------- cls kernel: 80 channels at matched cells only (exact fp32) ----------
__global__ __launch_bounds__(128) void cls_kernel(const float* __restrict__ xin,
    const float* __restrict__ cw, const float* __restrict__ cb, float* __restrict__ ws){
  const int cnt = ((const int*)ws)[CNT_O];
  if ((int)blockIdx.x >= cnt) return;
  const int cA  = ((const int*)ws)[LIST_O + blockIdx.x*2];
  const int cls = ((const int*)ws)[LIST_O + blockIdx.x*2 + 1];
  const int b   = cA / (AD*FFD);
  const int rem = cA - b*AD*FFD;
  const int a   = rem / FFD;
  const int hw  = rem - a*FFD;
  __shared__ float xs[256];
  __shared__ float sm[128];
  const int tid = threadIdx.x;
  const float* xb = xin + ((size_t)b*CD)*FFD + hw;
  xs[tid]       = xb[(size_t)tid*FFD];
  xs[tid + 128] = xb[(size_t)(tid + 128)*FFD];
  __syncthreads();
  float lcls = 0.f, l2p = 0.f;
  if (tid < 80){
    const int o = a*85 + 5 + tid;
    const float* wr = cw + o*CD;
    float s = 0.f;
    #pragma unroll 8
    for (int c = 0; c < CD; ++c) s += xs[c]*wr[c];
    const float e = sigm(s + cb[o]);
    const float t = (tid == cls) ? 1.f : 0.f;
    lcls = bce(e, t);
    l2p  = (e - t)*(e - t);
  }
  sm[tid] = lcls; __syncthreads();
  for (int s2 = 64; s2 > 0; s2 >>= 1){ if (tid < s2) sm[tid] += sm[tid+s2]; __syncthreads(); }
  if (tid == 0) atomicAdd(ws + ACC_O + 3, sm[0]);
  __syncthreads();
  sm[tid] = l2p; __syncthreads();
  for (int s2 = 64; s2 > 0; s2 >>= 1){ if (tid < s2) sm[tid] += sm[tid+s2]; __syncthreads(); }
  if (tid == 0) atomicAdd(ws + ACC_O + 4, sm[0]);
}

// ---------------- finalize ------------------------------------------------------------
__global__ __launch_bounds__(256) void fin_kernel(const float* __restrict__ ws,
                                                  float* __restrict__ out){
  __shared__ float sm[256];
  const int tid = threadIdx.x;
  float p[4] = {0,0,0,0};
  for (int i = tid; i < NBLK; i += 256){
    p[0] += ws[BLK_O + i*4 + 0];
    p[1] += ws[BLK_O + i*4 + 1];
    p[2] += ws[BLK_O + i*4 + 2];
    p[3] += ws[BLK_O + i*4 + 3];
  }
  float tot[4];
  #pragma unroll
  for (int r = 0; r < 4; ++r){
    __syncthreads();
    sm[tid] = p[r];
    __syncthreads();
    for (int s = 128; s > 0; s >>= 1){
      if (tid < s) sm[tid] += sm[tid + s];
      __syncthreads();
    }
    tot[r] = sm[0];
  }
  if (tid == 0){
    const float lxy = tot[0], lwh = tot[1], lobj = tot[2];
    const float lcls = ws[ACC_O+3];
    const float l2   = tot[3] + ws[ACC_O+4];
    out[0] = lxy + lwh + lobj + lcls;
    out[1] = lxy; out[2] = lwh; out[3] = lobj; out[4] = lcls; out[5] = l2;
  }
}

extern "C" void kernel_launch(void* const* d_in, const int* in_sizes, int n_in,
                              void* d_out, int out_size, void* d_ws, size_t ws_size,
                              hipStream_t stream){
  const float* xin    = (const float*)d_in[0];
  const float* labels = (const float*)d_in[1];
  const float* cw     = (const float*)d_in[2];
  const float* cb     = (const float*)d_in[3];
  float* out = (float*)d_out;
  float* ws  = (float*)d_ws;
  unsigned short* xbf = (unsigned short*)(ws + XBF_O);

  label_kernel<<<5, 256, 0, stream>>>(labels, cw, ws);
  convert_kernel<<<2048, 256, 0, stream>>>((const f32x4*)xin, xbf);
  fused_kernel<<<NBLK, 384, 0, stream>>>(xbf, ws + WP_O, cb, ws, ws + TREC_O);
  cls_kernel<<<800, 128, 0, stream>>>(xin, cw, cb, ws);
  fin_kernel<<<1, 256, 0, stream>>>(ws, out);
}

// Round 11
// 53.303 us; speedup vs baseline: 1.8913x; 1.7661x over previous
//
#include <hip/hip_runtime.h>
#include <math.h>

#define FD 76
#define FFD 5776
#define BD 16
#define CD 256
#define KD 50
#define AD 3

typedef float f32x2 __attribute__((ext_vector_type(2)));
typedef float f32x4 __attribute__((ext_vector_type(4)));

constexpr int NCELL = BD * FFD;          // 92416
constexpr int CBLK  = 128;               // cells per block
constexpr int NBLK  = NCELL / CBLK;      // 722

// ws layout (float offsets)
constexpr int ACC_O  = 0;                // [8]: [3]=lcls, [4]=l2cls (cls-kernel atomics)
constexpr int CNT_O  = 8;                // [1] int match counter
constexpr int LIST_O = 16;               // [1024][2] ints (cA, cls)
constexpr int TREC_O = 2064;             // [800][16] per-(b,k) records (16B aligned)
constexpr int BLK_O  = TREC_O + 800*16;  // [NBLK*4] per-block loss partials

__device__ __forceinline__ float sigm(float x){ return 1.f/(1.f + expf(-x)); }
__device__ __forceinline__ float clg(float x){ return logf(fmaxf(x, 1e-12f)); }
__device__ __forceinline__ float bce(float o, float t){ return -(t*clg(o) + (1.f-t)*clg(1.f-o)); }

// record layout [16]: 0:tx0 1:tx1 2:ty0 3:ty1 4:c7(0.7*ta) 5:code 6:txf 7:tyf
//                     8:twl 9:thl 10:scale 11:cls 12..15 pad
__global__ __launch_bounds__(256) void label_kernel(const float* __restrict__ labels,
                                                    float* __restrict__ ws){
  const int it = blockIdx.x*256 + threadIdx.x;
  if (blockIdx.x == 0 && threadIdx.x < 9){
    if (threadIdx.x < 8) ws[ACC_O + threadIdx.x] = 0.f;
    else ((int*)ws)[CNT_O] = 0;
  }
  if (it >= BD*KD) return;
  const float AWH[9][2] = {{1.25f,1.625f},{2.f,3.75f},{4.125f,2.875f},
                           {3.75f,7.625f},{7.75f,5.625f},{7.375f,14.875f},
                           {14.5f,11.25f},{19.5f,24.75f},{46.625f,40.75f}};
  const float* l = labels + it*5;
  const float cls = l[0], x = l[1], y = l[2], w = l[3], h = l[4];
  const bool valid = (cls + x + y + w + h) > 0.f;
  const float tx = x*FD, ty = y*FD, tw = w*FD, th = h*FD;
  const float ta = tw*th;
  float bestv = -1.f; int best = 0;
  #pragma unroll
  for (int n = 0; n < 9; ++n){
    const float mw = fminf(tw, AWH[n][0]), mh = fminf(th, AWH[n][1]);
    const float inter = (mw > 0.f && mh > 0.f) ? mw*mh : 0.f;
    const float iou = inter / (ta + AWH[n][0]*AWH[n][1] - inter);
    if (iou > bestv){ bestv = iou; best = n; }
  }
  const int bn = best % 3;
  const bool match = valid && (best < 3);
  const int ii = (int)tx, jj = (int)ty;
  const bool inb = (ii >= 0 && ii < FD && jj >= 0 && jj < FD);
  const float code = (match && inb) ? (float)(bn*FFD + jj*FD + ii) : -1.f;
  const float aw0 = (bn==0)?1.25f:((bn==1)?2.f:4.125f);
  const float aw1 = (bn==0)?1.625f:((bn==1)?3.75f:2.875f);
  float* r = ws + TREC_O + it*16;
  f32x4 r0 = {tx - tw*0.5f, tx + tw*0.5f, ty - th*0.5f, ty + th*0.5f};
  f32x4 r1 = {valid ? 0.7f*ta : 1e30f, code, tx - floorf(tx), ty - floorf(ty)};
  f32x4 r2 = {logf(tw/aw0 + 1e-16f), logf(th/aw1 + 1e-16f),
              sqrtf(2.f - ta/(float)(FD*FD)), cls};
  f32x4 r3 = {0.f, 0.f, 0.f, 0.f};
  *(f32x4*)(r+0) = r0; *(f32x4*)(r+4) = r1; *(f32x4*)(r+8) = r2; *(f32x4*)(r+12) = r3;
}

// ---------------- fused conv + epilogue (match resolve + IoU + losses) ----------------
// 722 blocks x 256 threads. Block = 128 cells (2/lane); wave wv does 64 channels.
__global__ __launch_bounds__(256) void fused_kernel(const float* __restrict__ xin,
    const float* __restrict__ cw, const float* __restrict__ cb, float* __restrict__ ws){
  __shared__ __align__(16) float lds[1600 + 7680]; // trec[2][50][16] | wT[256][16] / comb[4][15][128]
  float* trec  = lds;
  float* phase = lds + 1600;
  const int tid  = threadIdx.x;
  const int wv   = tid >> 6;
  const int lane = tid & 63;

  const int cell0blk = blockIdx.x*CBLK;
  const int bB0 = cell0blk / FFD;
  const int bB1 = (bB0 + 1 < BD) ? bB0 + 1 : bB0;

  // stage 2 batches of records (400 f32x4)
  {
    const f32x4* src = (const f32x4*)(ws + TREC_O);
    f32x4* dst = (f32x4*)trec;
    int q = tid;
    dst[q] = (q < 200) ? src[bB0*200 + q] : src[bB1*200 + q - 200];
    q = tid + 256;
    if (q < 400) dst[q] = src[bB1*200 + q - 200];
  }
  // stage 15 W rows: wT[c*16+j] = cw[o(j)*256+c]
  #pragma unroll
  for (int j = 0; j < 15; ++j){
    const int o = (j/5)*85 + (j%5);
    phase[tid*16 + j] = cw[o*CD + tid];
  }
  phase[tid*16 + 15] = 0.f;
  __syncthreads();

  // ---- conv: lane owns cells (cell0blk + 2*lane, +1); wave owns 64 channels ----
  const int cellP = cell0blk + 2*lane;
  const int bC  = cellP / FFD;
  const int hwC = cellP - bC*FFD;
  const float* xp = xin + ((size_t)bC*CD + wv*64)*FFD + hwC;

  f32x2 acc[15];
  #pragma unroll
  for (int j = 0; j < 15; ++j) acc[j] = (f32x2){0.f, 0.f};

  f32x2 xr[16], xn[16];
  #pragma unroll
  for (int i = 0; i < 16; ++i) xr[i] = *(const f32x2*)(xp + (size_t)i*FFD);
  #pragma unroll
  for (int cc = 0; cc < 4; ++cc){
    if (cc < 3){
      #pragma unroll
      for (int i = 0; i < 16; ++i)
        xn[i] = *(const f32x2*)(xp + (size_t)((cc+1)*16 + i)*FFD);
    }
    #pragma unroll
    for (int i = 0; i < 16; ++i){
      const int c = wv*64 + cc*16 + i;
      const f32x4* wr = (const f32x4*)&phase[c*16];
      const f32x4 w0 = wr[0], w1 = wr[1], w2 = wr[2], w3 = wr[3];
      const f32x2 xv = xr[i];
      acc[0]  += w0.x*xv; acc[1]  += w0.y*xv; acc[2]  += w0.z*xv; acc[3]  += w0.w*xv;
      acc[4]  += w1.x*xv; acc[5]  += w1.y*xv; acc[6]  += w1.z*xv; acc[7]  += w1.w*xv;
      acc[8]  += w2.x*xv; acc[9]  += w2.y*xv; acc[10] += w2.z*xv; acc[11] += w2.w*xv;
      acc[12] += w3.x*xv; acc[13] += w3.y*xv; acc[14] += w3.z*xv;
    }
    if (cc < 3){
      #pragma unroll
      for (int i = 0; i < 16; ++i) xr[i] = xn[i];
    }
  }

  __syncthreads();                         // done reading wT
  // comb[wv][j][cell], j-major stride 128
  #pragma unroll
  for (int j = 0; j < 15; ++j)
    *(f32x2*)&phase[wv*1920 + j*128 + 2*lane] = acc[j];
  __syncthreads();

  // ---- epilogue: 384 (cell,anchor) items; threads 0..191 take item pair (2t,2t+1) ----
  float lxy = 0.f, lwh = 0.f, lobj = 0.f, l2p = 0.f;
  if (tid < 192){
    const int it0 = 2*tid;
    const int a = it0 >> 7;
    const int cell0 = it0 & 127, cell1 = cell0 + 1;
    const float mw0 = (a==0)?1.25f:((a==1)?2.f:4.125f);
    const float mw1 = (a==0)?1.625f:((a==1)?3.75f:2.875f);
    float v0[5], v1[5];
    #pragma unroll
    for (int jj = 0; jj < 5; ++jj){
      const float bias = cb[a*85 + jj];
      float s0 = bias, s1 = bias;
      #pragma unroll
      for (int w2 = 0; w2 < 4; ++w2){
        const f32x2 q = *(const f32x2*)&phase[w2*1920 + (a*5+jj)*128 + cell0];
        s0 += q.x; s1 += q.y;
      }
      v0[jj] = s0; v1[jj] = s1;
    }
    const int g0 = cell0blk + cell0;
    const int bb = g0 / FFD;
    const int hw0 = g0 - bb*FFD,  hw1 = hw0 + 1;
    const int hh0 = hw0 / FD, wc0 = hw0 - hh0*FD;
    const int hh1 = hw1 / FD, wc1 = hw1 - hh1*FD;

    const float sx0 = sigm(v0[0]), sy0 = sigm(v0[1]), so0 = sigm(v0[4]);
    const float sx1 = sigm(v1[0]), sy1 = sigm(v1[1]), so1 = sigm(v1[4]);
    const float pw0 = expf(v0[2])*mw0, ph0 = expf(v0[3])*mw1;
    const float pw1 = expf(v1[2])*mw0, ph1 = expf(v1[3])*mw1;
    const float px0a = sx0 + wc0 - pw0*0.5f, px0b = sx0 + wc0 + pw0*0.5f;
    const float py0a = sy0 + hh0 - ph0*0.5f, py0b = sy0 + hh0 + ph0*0.5f;
    const float px1a = sx1 + wc1 - pw1*0.5f, px1b = sx1 + wc1 + pw1*0.5f;
    const float py1a = sy1 + hh1 - ph1*0.5f, py1b = sy1 + hh1 + ph1*0.5f;
    const float s7_0 = 0.7f*pw0*ph0, s7_1 = 0.7f*pw1*ph1;
    const float code0 = (float)(a*FFD + hw0), code1 = (float)(a*FFD + hw1);

    const float* rb = trec + ((bb == bB0) ? 0 : 800);
    float mx0 = -1e30f, mx1 = -1e30f;
    int ks0 = -1, ks1 = -1;
    for (int k = 0; k < KD; ++k){
      const f32x4 rA = *(const f32x4*)&rb[k*16];      // tx0 tx1 ty0 ty1
      const f32x2 rB = *(const f32x2*)&rb[k*16 + 4];  // c7, code
      {
        const float dx = fminf(px0b, rA.y) - fmaxf(px0a, rA.x);
        const float dy = fminf(py0b, rA.w) - fmaxf(py0a, rA.z);
        const float inter = fmaxf(dx, 0.f)*fmaxf(dy, 0.f);
        mx0 = fmaxf(mx0, 1.7f*inter - rB.x);
        ks0 = (rB.y == code0) ? k : ks0;
      }
      {
        const float dx = fminf(px1b, rA.y) - fmaxf(px1a, rA.x);
        const float dy = fminf(py1b, rA.w) - fmaxf(py1a, rA.z);
        const float inter = fmaxf(dx, 0.f)*fmaxf(dy, 0.f);
        mx1 = fmaxf(mx1, 1.7f*inter - rB.x);
        ks1 = (rB.y == code1) ? k : ks1;
      }
    }
    // item 0
    if (ks0 >= 0){
      const f32x2 p0 = *(const f32x2*)&rb[ks0*16 + 6];
      const f32x4 p1 = *(const f32x4*)&rb[ks0*16 + 8];
      const float sc = p1.z, sc2 = sc*sc;
      lxy += sc2*(bce(sx0, p0.x) + bce(sy0, p0.y));
      l2p += (sx0-p0.x)*(sx0-p0.x) + (sy0-p0.y)*(sy0-p0.y);
      const float d0 = v0[2]-p1.x, d1 = v0[3]-p1.y;
      lwh += 0.5f*sc2*(d0*d0 + d1*d1);
      l2p += sc2*(d0*d0 + d1*d1);
      lobj += -clg(so0); l2p += (so0-1.f)*(so0-1.f);
      const int pos = atomicAdd((int*)ws + CNT_O, 1);
      if (pos < 1024){ ((int*)ws)[LIST_O + pos*2] = (bb*AD + a)*FFD + hw0;
                       ((int*)ws)[LIST_O + pos*2 + 1] = (int)p1.w; }
    } else if (!(mx0 > s7_0)){ lobj += -clg(1.f - so0); l2p += so0*so0; }
    // item 1
    if (ks1 >= 0){
      const f32x2 p0 = *(const f32x2*)&rb[ks1*16 + 6];
      const f32x4 p1 = *(const f32x4*)&rb[ks1*16 + 8];
      const float sc = p1.z, sc2 = sc*sc;
      lxy += sc2*(bce(sx1, p0.x) + bce(sy1, p0.y));
      l2p += (sx1-p0.x)*(sx1-p0.x) + (sy1-p0.y)*(sy1-p0.y);
      const float d0 = v1[2]-p1.x, d1 = v1[3]-p1.y;
      lwh += 0.5f*sc2*(d0*d0 + d1*d1);
      l2p += sc2*(d0*d0 + d1*d1);
      lobj += -clg(so1); l2p += (so1-1.f)*(so1-1.f);
      const int pos = atomicAdd((int*)ws + CNT_O, 1);
      if (pos < 1024){ ((int*)ws)[LIST_O + pos*2] = (bb*AD + a)*FFD + hw1;
                       ((int*)ws)[LIST_O + pos*2 + 1] = (int)p1.w; }
    } else if (!(mx1 > s7_1)){ lobj += -clg(1.f - so1); l2p += so1*so1; }
  }

  #pragma unroll
  for (int o = 32; o > 0; o >>= 1){
    lxy  += __shfl_down(lxy,  o, 64);
    lwh  += __shfl_down(lwh,  o, 64);
    lobj += __shfl_down(lobj, o, 64);
    l2p  += __shfl_down(l2p,  o, 64);
  }
  __syncthreads();
  if (lane == 0){
    lds[wv*4+0] = lxy; lds[wv*4+1] = lwh; lds[wv*4+2] = lobj; lds[wv*4+3] = l2p;
  }
  __syncthreads();
  if (tid < 4)
    ws[BLK_O + blockIdx.x*4 + tid] =
      lds[0*4+tid] + lds[1*4+tid] + lds[2*4+tid] + lds[3*4+tid];
}

// ---------------- cls kernel: 80 channels at matched cells only (256 thr: 1 load ea) --
__global__ __launch_bounds__(256) void cls_kernel(const float* __restrict__ xin,
    const float* __restrict__ cw, const float* __restrict__ cb, float* __restrict__ ws){
  const int cnt = ((const int*)ws)[CNT_O];
  if ((int)blockIdx.x >= cnt) return;
  const int cA  = ((const int*)ws)[LIST_O + blockIdx.x*2];
  const int cls = ((const int*)ws)[LIST_O + blockIdx.x*2 + 1];
  const int b   = cA / (AD*FFD);
  const int rem = cA - b*AD*FFD;
  const int a   = rem / FFD;
  const int hw  = rem - a*FFD;
  __shared__ float xs[256];
  __shared__ float sm[256];
  const int tid = threadIdx.x;
  const float* xb = xin + ((size_t)b*CD)*FFD + hw;
  xs[tid] = xb[(size_t)tid*FFD];           // one strided load per thread
  __syncthreads();
  float lcls = 0.f, l2p = 0.f;
  if (tid < 80){
    const int o = a*85 + 5 + tid;
    const float* wr = cw + o*CD;
    float s = 0.f;
    #pragma unroll 8
    for (int c = 0; c < CD; ++c) s += xs[c]*wr[c];
    const float e = sigm(s + cb[o]);
    const float t = (tid == cls) ? 1.f : 0.f;
    lcls = bce(e, t);
    l2p  = (e - t)*(e - t);
  }
  sm[tid] = lcls; __syncthreads();
  for (int s2 = 128; s2 > 0; s2 >>= 1){ if (tid < s2) sm[tid] += sm[tid+s2]; __syncthreads(); }
  if (tid == 0) atomicAdd(ws + ACC_O + 3, sm[0]);
  __syncthreads();
  sm[tid] = l2p; __syncthreads();
  for (int s2 = 128; s2 > 0; s2 >>= 1){ if (tid < s2) sm[tid] += sm[tid+s2]; __syncthreads(); }
  if (tid == 0) atomicAdd(ws + ACC_O + 4, sm[0]);
}

// ---------------- finalize ------------------------------------------------------------
__global__ __launch_bounds__(256) void fin_kernel(const float* __restrict__ ws,
                                                  float* __restrict__ out){
  __shared__ float sm[256];
  const int tid = threadIdx.x;
  float p[4] = {0,0,0,0};
  for (int i = tid; i < NBLK; i += 256){
    p[0] += ws[BLK_O + i*4 + 0];
    p[1] += ws[BLK_O + i*4 + 1];
    p[2] += ws[BLK_O + i*4 + 2];
    p[3] += ws[BLK_O + i*4 + 3];
  }
  float tot[4];
  #pragma unroll
  for (int r = 0; r < 4; ++r){
    __syncthreads();
    sm[tid] = p[r];
    __syncthreads();
    for (int s = 128; s > 0; s >>= 1){
      if (tid < s) sm[tid] += sm[tid + s];
      __syncthreads();
    }
    tot[r] = sm[0];
  }
  if (tid == 0){
    const float lxy = tot[0], lwh = tot[1], lobj = tot[2];
    const float lcls = ws[ACC_O+3];
    const float l2   = tot[3] + ws[ACC_O+4];
    out[0] = lxy + lwh + lobj + lcls;
    out[1] = lxy; out[2] = lwh; out[3] = lobj; out[4] = lcls; out[5] = l2;
  }
}

extern "C" void kernel_launch(void* const* d_in, const int* in_sizes, int n_in,
                              void* d_out, int out_size, void* d_ws, size_t ws_size,
                              hipStream_t stream){
  const float* xin    = (const float*)d_in[0];
  const float* labels = (const float*)d_in[1];
  const float* cw     = (const float*)d_in[2];
  const float* cb     = (const float*)d_in[3];
  float* out = (float*)d_out;
  float* ws  = (float*)d_ws;

  label_kernel<<<4, 256, 0, stream>>>(labels, ws);
  fused_kernel<<<NBLK, 256, 0, stream>>>(xin, cw, cb, ws);
  cls_kernel<<<800, 256, 0, stream>>>(xin, cw, cb, ws);
  fin_kernel<<<1, 256, 0, stream>>>(ws, out);
}